// Round 3
// 538.973 us; speedup vs baseline: 1.3298x; 1.3298x over previous
//
#include <hip/hip_runtime.h>

typedef float  f4  __attribute__((ext_vector_type(4)));
typedef __bf16 bf8 __attribute__((ext_vector_type(8)));
typedef short  s8  __attribute__((ext_vector_type(8)));
typedef int    i2  __attribute__((ext_vector_type(2)));
typedef double d2v __attribute__((ext_vector_type(2)));

__device__ inline unsigned short f2bf_bits(float f) {
    unsigned u = __float_as_uint(f);
    u += 0x7fffu + ((u >> 16) & 1u);   // RNE to bf16
    return (unsigned short)(u >> 16);
}

// ---------------- W transpose + bf16 convert: Wt[n][k] = bf16(W[k][n]) ----------------
__global__ __launch_bounds__(256) void wtrans_kernel(const float* __restrict__ W,
                                                     unsigned short* __restrict__ Wt) {
    int idx = blockIdx.x * 256 + threadIdx.x;
    if (idx < 768 * 128) {
        int k = idx >> 7, n = idx & 127;
        Wt[n * 768 + k] = f2bf_bits(W[idx]);
    }
}

// ---------------- projection: Out = bf16(l2norm(In @ W + b)), 128-row tiles ----------------
__global__ __launch_bounds__(256) void proj_kernel(const float* __restrict__ In,
                                                   const unsigned short* __restrict__ Wt,
                                                   const float* __restrict__ bias,
                                                   unsigned short* __restrict__ Out) {
    int tid = threadIdx.x;
    int wave = tid >> 6, lane = tid & 63;
    int quad = lane >> 4, rq = lane & 15;
    int rh = (wave >> 1) * 64, ch = (wave & 1) * 64;
    long rowBase = (long)blockIdx.x * 128 + rh;

    f4 acc[4][4];
#pragma unroll
    for (int a = 0; a < 4; ++a)
#pragma unroll
        for (int b = 0; b < 4; ++b) acc[a][b] = 0.0f;

    for (int kc = 0; kc < 24; ++kc) {
        int k0 = kc * 32 + quad * 8;
        bf8 af[4], bfr[4];
#pragma unroll
        for (int t = 0; t < 4; ++t) {
            const float* ap = In + (rowBase + t * 16 + rq) * 768 + k0;
            f4 u0 = *(const f4*)ap;
            f4 u1 = *(const f4*)(ap + 4);
            s8 tmp;
            tmp[0] = (short)f2bf_bits(u0[0]); tmp[1] = (short)f2bf_bits(u0[1]);
            tmp[2] = (short)f2bf_bits(u0[2]); tmp[3] = (short)f2bf_bits(u0[3]);
            tmp[4] = (short)f2bf_bits(u1[0]); tmp[5] = (short)f2bf_bits(u1[1]);
            tmp[6] = (short)f2bf_bits(u1[2]); tmp[7] = (short)f2bf_bits(u1[3]);
            af[t] = __builtin_bit_cast(bf8, tmp);
            bfr[t] = *(const bf8*)(const void*)(Wt + (ch + t * 16 + rq) * 768 + k0);
        }
#pragma unroll
        for (int ti = 0; ti < 4; ++ti)
#pragma unroll
            for (int tj = 0; tj < 4; ++tj)
                acc[ti][tj] = __builtin_amdgcn_mfma_f32_16x16x32_bf16(af[ti], bfr[tj], acc[ti][tj], 0, 0, 0);
    }

    __shared__ float ssq[128];
    if (tid < 128) ssq[tid] = 0.f;
    __syncthreads();

    float b4[4];
#pragma unroll
    for (int tj = 0; tj < 4; ++tj) b4[tj] = bias[ch + tj * 16 + rq];

#pragma unroll
    for (int ti = 0; ti < 4; ++ti)
#pragma unroll
        for (int r = 0; r < 4; ++r) {
            float p = 0.f;
#pragma unroll
            for (int tj = 0; tj < 4; ++tj) {
                float z = acc[ti][tj][r] + b4[tj];
                p += z * z;
            }
            atomicAdd(&ssq[rh + ti * 16 + quad * 4 + r], p);
        }
    __syncthreads();

#pragma unroll
    for (int ti = 0; ti < 4; ++ti)
#pragma unroll
        for (int r = 0; r < 4; ++r) {
            int rowL = rh + ti * 16 + quad * 4 + r;
            float rn = rsqrtf(ssq[rowL]);
#pragma unroll
            for (int tj = 0; tj < 4; ++tj) {
                float z = (acc[ti][tj][r] + b4[tj]) * rn;
                Out[((long)blockIdx.x * 128 + rowL) * 128 + ch + tj * 16 + rq] = f2bf_bits(z);
            }
        }
}

// ------- gram: E[b][i][d=i+j] = bf16(exp((2*dot-2)*10)) = exp(-D/gamma), diagonal stream -------
__global__ __launch_bounds__(256) void gram_kernel(const unsigned short* __restrict__ X,
                                                   const unsigned short* __restrict__ Y,
                                                   unsigned short* __restrict__ S,
                                                   int N, int M, int Nd8) {
    int b = blockIdx.z;
    long i0 = (long)blockIdx.x * 128, j0 = (long)blockIdx.y * 128;
    const unsigned short* Xb = X + (long)b * N * 128;
    const unsigned short* Yb = Y + (long)b * M * 128;
    unsigned short* Sb = S + (long)b * N * Nd8;
    int tid = threadIdx.x, wave = tid >> 6, lane = tid & 63;
    int quad = lane >> 4, rq = lane & 15;
    int rh = (wave >> 1) * 64, ch = (wave & 1) * 64;

    f4 acc[4][4];
#pragma unroll
    for (int a = 0; a < 4; ++a)
#pragma unroll
        for (int c = 0; c < 4; ++c) acc[a][c] = 0.0f;

#pragma unroll
    for (int kc = 0; kc < 4; ++kc) {
        int k0 = kc * 32 + quad * 8;
        bf8 af[4], bfr[4];
#pragma unroll
        for (int t = 0; t < 4; ++t) {
            af[t]  = *(const bf8*)(const void*)(Xb + (i0 + rh + t * 16 + rq) * 128 + k0);
            bfr[t] = *(const bf8*)(const void*)(Yb + (j0 + ch + t * 16 + rq) * 128 + k0);
        }
#pragma unroll
        for (int ti = 0; ti < 4; ++ti)
#pragma unroll
            for (int tj = 0; tj < 4; ++tj)
                acc[ti][tj] = __builtin_amdgcn_mfma_f32_16x16x32_bf16(af[ti], bfr[tj], acc[ti][tj], 0, 0, 0);
    }

#pragma unroll
    for (int ti = 0; ti < 4; ++ti)
#pragma unroll
        for (int r = 0; r < 4; ++r) {
            long gi = i0 + rh + ti * 16 + quad * 4 + r;
#pragma unroll
            for (int tj = 0; tj < 4; ++tj) {
                long gj = j0 + ch + tj * 16 + rq;
                float Ev = __expf(20.0f * acc[ti][tj][r] - 20.0f);
                Sb[gi * Nd8 + gi + gj] = f2bf_bits(Ev);
            }
        }
}

// ---------------- soft-DTW alpha-space DP (fp64) ----------------
// 4-wave cooperative wavefront per (batch, matrix). Rows split across waves;
// bottom-row alphas relayed wave->wave through LDS in 16-step chunks. Each wave has its
// own pow2 scale frame ls (invariant: stored = true * 2^ls); handoff values carry the
// writer's ls per 8-step half-group and are re-framed via exact ldexp(raw, ls_r - ls_w).
// A unified pre-anchor per chunk folds the incoming injection magnitudes into the
// rescale decision: first-contact frame adoption (own field zero -> direct ls set) and
// a guarantee that injections land at <= 2^870 (no overflow); injections >~134 cost
// units below the reader's max underflow to 0, which the depth argument makes exact.
__device__ inline double wshr1_d(double x) {  // lane l <- lane l-1, lane 0 <- 0
    i2 v = __builtin_bit_cast(i2, x);
    v.x = __builtin_amdgcn_update_dpp(0, v.x, 0x138, 0xf, 0xf, false);
    v.y = __builtin_amdgcn_update_dpp(0, v.y, 0x138, 0xf, 0xf, false);
    return __builtin_bit_cast(double, v);
}
#define DPPMAXI(x, ctrl) max((x), __builtin_amdgcn_update_dpp(0, (x), (ctrl), 0xf, 0xf, false))
__device__ inline int redmax64_i(int x) {   // full max in lane 63 (patterns >= 0)
    x = DPPMAXI(x, 0x111);  // row_shr:1
    x = DPPMAXI(x, 0x112);  // row_shr:2
    x = DPPMAXI(x, 0x114);  // row_shr:4
    x = DPPMAXI(x, 0x118);  // row_shr:8
    x = DPPMAXI(x, 0x142);  // row_bcast15
    x = DPPMAXI(x, 0x143);  // row_bcast31
    return x;
}
__device__ inline int hiw(double x) { return __builtin_bit_cast(i2, x).y; }

// K rows/lane PER WAVE; NWAVE waves; rows per wave NW = 64*K; N = NWAVE*NW.
template<int K, int N, int M, int ND8, int NWAVE>
static __device__ __attribute__((always_inline))
void dp_impl(const unsigned short* __restrict__ E, float wscale,
             float* __restrict__ out, char* __restrict__ smem) {
    constexpr int NW    = K * 64;              // rows handled by one wave
    constexpr int BLEN  = NW + M - 1;          // local diag count (odd for our shapes)
    constexpr int NCH   = (BLEN + 15) / 16;    // 16-step chunks per wave
    constexpr int BPAD  = NCH * 16;            // padded boundary buffer length
    constexpr int SLEN  = BPAD / 8;            // scale slots (one per 8-step half-group)
    constexpr int LAG   = NW / 16 + 1;         // chunk lag between adjacent waves
    constexpr int ROUNDS = (NWAVE - 1) * LAG + NCH;

    const int tid  = threadIdx.x;
    const int lane = tid & 63;
    const int w    = tid >> 6;                 // wave id = row-block id

    double* bvAll = (double*)smem;                                  // (NWAVE-1) x BPAD
    int*    scAll = (int*)(smem + (size_t)(NWAVE - 1) * BPAD * 8);  // (NWAVE-1) x SLEN

    const char* Eb = (const char*)(E + (long)blockIdx.x * N * ND8);
    unsigned off[K];
    uint4 eA[K], eB[K];
    double vA[K], vB[K];
#pragma unroll
    for (int r = 0; r < K; ++r) {
        // wave w's rows start at w*NW; its local diag 0 is global diag w*NW
        off[r] = (unsigned)((((long)(w * NW + K * lane + r)) * ND8 + (long)(w * NW)) * 2);
        vA[r] = 0.0; vB[r] = 0.0;
    }
    int ls = 0;                               // accumulated log2 scale (wave-uniform)

#define EGETV(EQ, PH) __uint_as_float(((PH) & 1) ? ((&(EQ).x)[(PH) >> 1] & 0xffff0000u) \
                                                 : ((&(EQ).x)[(PH) >> 1] << 16))
    // one anti-diagonal: writes W (held A[d-2], becomes A[d]), reads P1 (= A[d-1]).
    // S2/S1 inject the upstream-wave boundary (diag / above) into lane 0; exact +0.0 elsewhere.
#define DSTEP(W, P1, EB_, PH, S2, S1) do { \
        double b1 = wshr1_d(P1[K - 1]) + (S1); \
        double b2 = wshr1_d(W[K - 1]) + (S2); \
        double p2 = b2, p1m = b1; \
        _Pragma("unroll") \
        for (int r = 0; r < K; ++r) { \
            double told = W[r]; double c1 = P1[r]; \
            double Ed = (double)EGETV(EB_[r], PH); \
            W[r] = Ed * (p2 + p1m + c1); \
            p2 = told; p1m = c1; \
        } } while (0)

    // pow2 rescale of BOTH live diagonals, anchor 2^870 (biased 1893). Headroom above
    // anchor 2^154 = e^107 covers the e^40 boundary-coupling bound; depth below anchor
    // (870+1074) bits = 134.7 cost units > ~82 needed, so nothing reachable is flushed.
#define DRESC(W, P1) do { \
        int hm = hiw(W[0]) > hiw(P1[0]) ? hiw(W[0]) : hiw(P1[0]); \
        _Pragma("unroll") \
        for (int r = 1; r < K; ++r) { \
            int h1 = hiw(W[r]), h2 = hiw(P1[r]); \
            if (h1 > hm) hm = h1; if (h2 > hm) hm = h2; } \
        hm = redmax64_i(hm); \
        int hb = __builtin_amdgcn_readlane(hm, 63); \
        if (hb > 0) { \
            int eraw2 = (hb >> 20) & 0x7ff; \
            int sh = 1893 - eraw2;                     /* target exponent 2^870 */ \
            sh = (sh > 1020) ? 1020 : ((sh < -1020) ? -1020 : sh); \
            i2 fb; fb.x = 0; fb.y = (1023 + sh) << 20; \
            double f = __builtin_bit_cast(double, fb); \
            ls += sh; \
            _Pragma("unroll") \
            for (int r = 0; r < K; ++r) { W[r] *= f; P1[r] *= f; } \
        } } while (0)

    for (int round = 0; round < ROUNDS; ++round) {
        const int c = round - w * LAG;         // this wave's chunk index (wave-uniform)
        if (c >= 0 && c < NCH) {
            // ---- boundary raw reads (broadcast, conflict-free). Entry g holds upstream
            // bottom-row alpha at column j' = g-(NW-1); step s uses entries gb+s (diag) and
            // gb+s+1 (above). NW ≡ 0 mod 8 so gb ≡ 6 mod 8: scale-slot offsets are static.
            double raw[17]; int sc3[3];
            const int gb = NW - 2 + 16 * c;
            if (w > 0) {
                const double* bvR = bvAll + (size_t)(w - 1) * BPAD;
                const int*    scR = scAll + (w - 1) * SLEN;
#pragma unroll
                for (int i = 0; i < 8; ++i) {
                    int idx = gb + 2 * i; if (idx > BPAD - 2) idx = BPAD - 2;  // clamped reads are masked below
                    d2v p = *(const d2v*)(bvR + idx);
                    raw[2 * i] = p.x; raw[2 * i + 1] = p.y;
                }
                int idx16 = gb + 16; if (idx16 > BPAD - 1) idx16 = BPAD - 1;
                raw[16] = bvR[idx16];
#pragma unroll
                for (int i = 0; i < 3; ++i) {
                    int s = (gb >> 3) + i; if (s > SLEN - 1) s = SLEN - 1;
                    sc3[i] = scR[s];
                }

                // ---- unified pre-anchor: fold own field max with incoming injection
                // magnitudes (reader frame), target 2^870. If own field is zero (first
                // contact), set ls directly (no multiply, unbounded jump safe on zeros).
                int hm0 = hiw(vA[0]) > hiw(vB[0]) ? hiw(vA[0]) : hiw(vB[0]);
#pragma unroll
                for (int r = 1; r < K; ++r) {
                    int h1 = hiw(vA[r]), h2 = hiw(vB[r]);
                    if (h1 > hm0) hm0 = h1; if (h2 > hm0) hm0 = h2;
                }
                hm0 = redmax64_i(hm0);
                int hbOwn = __builtin_amdgcn_readlane(hm0, 63);
                int ownEb = (hbOwn > 0) ? (hbOwn >> 20) : -1048576;
                int injEb = -1048576;
#pragma unroll
                for (int i = 0; i <= 16; ++i) {
                    int jp = 16 * c + i - 1;                 // column of raw[i]
                    int er = hiw(raw[i]) >> 20;              // biased exp (values >= 0)
                    int cand = er + (ls - sc3[(6 + i) >> 3]);
                    if (jp >= 0 && jp < M && er > 0 && cand > injEb) injEb = cand;
                }
                int MB = ownEb > injEb ? ownEb : injEb;
                if (MB > -1048576) {
                    int sh = 1893 - MB;
                    if (hbOwn > 0) {
                        sh = (sh > 1020) ? 1020 : ((sh < -1020) ? -1020 : sh);
                        i2 fb; fb.x = 0; fb.y = (1023 + sh) << 20;
                        double f = __builtin_bit_cast(double, fb);
#pragma unroll
                        for (int r = 0; r < K; ++r) { vA[r] *= f; vB[r] *= f; }
                    }
                    ls += sh;
                }
            }
            // ---- E loads: chunk = 16 diag entries = 32 bytes per row
            if (c == 0) {
#pragma unroll
                for (int r = 0; r < K; ++r) eA[r] = *(const uint4*)(const void*)(Eb + off[r]);
            }
#pragma unroll
            for (int r = 0; r < K; ++r) eB[r] = *(const uint4*)(const void*)(Eb + (off[r] + 16));

            // ---- injection values for steps 0-7, re-framed: stored_r = raw * 2^(ls_r - ls_w)
            double ca[9];
            if (w > 0) {
#pragma unroll
                for (int i = 0; i <= 8; ++i) {
                    int jp = 16 * c - 1 + i;           // upstream column j'
                    double v = fmin(ldexp(raw[i], ls - sc3[(6 + i) >> 3]), 8.9e307);
                    ca[i] = (lane == 0 && jp >= 0 && jp < M) ? v : 0.0;
                }
            } else {
#pragma unroll
                for (int i = 0; i <= 8; ++i) ca[i] = 0.0;
                if (c == 0 && lane == 0) ca[0] = 1.0;  // alpha[-1][-1] = 1 seed
            }

            double bb[8];                              // bottom-row collect for relay
            DSTEP(vA, vB, eA, 0, ca[0], ca[1]); bb[0] = vA[K - 1];
            DSTEP(vB, vA, eA, 1, ca[1], ca[2]); bb[1] = vB[K - 1];
            DSTEP(vA, vB, eA, 2, ca[2], ca[3]); bb[2] = vA[K - 1];
            DSTEP(vB, vA, eA, 3, ca[3], ca[4]); bb[3] = vB[K - 1];
            DSTEP(vA, vB, eA, 4, ca[4], ca[5]); bb[4] = vA[K - 1];
            DSTEP(vB, vA, eA, 5, ca[5], ca[6]); bb[5] = vB[K - 1];
            DSTEP(vA, vB, eA, 6, ca[6], ca[7]); bb[6] = vA[K - 1];
            DSTEP(vB, vA, eA, 7, ca[7], ca[8]); bb[7] = vB[K - 1];
            if (w < NWAVE - 1) {
                double* bvW = bvAll + (size_t)w * BPAD;
                int*    scW = scAll + w * SLEN;
                if (lane == 63) {
#pragma unroll
                    for (int i = 0; i < 4; ++i) {
                        d2v p; p.x = bb[2 * i]; p.y = bb[2 * i + 1];
                        *(d2v*)(bvW + 16 * c + 2 * i) = p;
                    }
                    scW[2 * c] = ls;                   // frame of the 8 values just written
                }
            }
            DRESC(vB, vA);
            if (c + 1 < NCH) {
#pragma unroll
                for (int r = 0; r < K; ++r) eA[r] = *(const uint4*)(const void*)(Eb + (off[r] + 32));
            }

            // ---- injection values for steps 8-15 (post-DRESC ls: current frame)
            double cb[9];
            if (w > 0) {
#pragma unroll
                for (int i = 0; i <= 8; ++i) {
                    int jp = 16 * c + 7 + i;
                    double v = fmin(ldexp(raw[8 + i], ls - sc3[(14 + i) >> 3]), 8.9e307);
                    cb[i] = (lane == 0 && jp < M) ? v : 0.0;
                }
            } else {
#pragma unroll
                for (int i = 0; i <= 8; ++i) cb[i] = 0.0;
            }

            DSTEP(vA, vB, eB, 0, cb[0], cb[1]); bb[0] = vA[K - 1];
            DSTEP(vB, vA, eB, 1, cb[1], cb[2]); bb[1] = vB[K - 1];
            DSTEP(vA, vB, eB, 2, cb[2], cb[3]); bb[2] = vA[K - 1];
            DSTEP(vB, vA, eB, 3, cb[3], cb[4]); bb[3] = vB[K - 1];
            DSTEP(vA, vB, eB, 4, cb[4], cb[5]); bb[4] = vA[K - 1];
            DSTEP(vB, vA, eB, 5, cb[5], cb[6]); bb[5] = vB[K - 1];
            DSTEP(vA, vB, eB, 6, cb[6], cb[7]); bb[6] = vA[K - 1];
            DSTEP(vB, vA, eB, 7, cb[7], cb[8]); bb[7] = vB[K - 1];
            if (w < NWAVE - 1) {
                double* bvW = bvAll + (size_t)w * BPAD;
                int*    scW = scAll + w * SLEN;
                if (lane == 63) {
#pragma unroll
                    for (int i = 0; i < 4; ++i) {
                        d2v p; p.x = bb[2 * i]; p.y = bb[2 * i + 1];
                        *(d2v*)(bvW + 16 * c + 8 + 2 * i) = p;
                    }
                    scW[2 * c + 1] = ls;
                }
            }
            DRESC(vB, vA);
#pragma unroll
            for (int r = 0; r < K; ++r) off[r] += 32;
        }
        // publish this round's LDS writes, then sync. Raw s_barrier (no vmcnt drain):
        // the in-flight E prefetches survive across the barrier.
        asm volatile("s_waitcnt lgkmcnt(0)\n\ts_barrier" ::: "memory");
    }

    if (w == NWAVE - 1 && lane == 63) {
        // A[N-1][M-1] at last-wave local diag BLEN-1 (even -> vA), row N-1 = lane 63, r = K-1
        double v = vA[K - 1];
        i2 vb2 = __builtin_bit_cast(i2, v);
        int eraw = (vb2.y >> 20) & 0x7ff;
        int ex = eraw - 1022;                       // v = m * 2^ex, m in [0.5,1)
        i2 mb; mb.x = vb2.x; mb.y = (vb2.y & 0x000FFFFF) | (1022 << 20);
        float mf = (float)__builtin_bit_cast(double, mb);
        if (!(mf > 0.f)) mf = 0.5f;                 // guard (cannot happen if DP sane)
        double R = -0.1 * ((double)logf(mf) + (double)(ex - ls) * 0.6931471805599453);
        atomicAdd(out, wscale * (float)R);
    }
#undef DSTEP
#undef DRESC
#undef EGETV
}

__global__ __launch_bounds__(256) void dp_kernel(const unsigned short* __restrict__ Sxy,
                                                 const unsigned short* __restrict__ Sxx,
                                                 const unsigned short* __restrict__ Syy,
                                                 float* __restrict__ out) {
    extern __shared__ char smem[];
    if (blockIdx.y == 0)      dp_impl<4, 1024,  768, 1792, 4>(Sxy,  1.0f / 28672.0f, out, smem);
    else if (blockIdx.y == 1) dp_impl<4, 1024, 1024, 2048, 4>(Sxx, -0.5f / 28672.0f, out, smem);
    else                      dp_impl<3,  768,  768, 1536, 4>(Syy, -0.5f / 28672.0f, out, smem);
}

// ---------------- host launcher ----------------
extern "C" void kernel_launch(void* const* d_in, const int* in_sizes, int n_in,
                              void* d_out, int out_size, void* d_ws, size_t ws_size,
                              hipStream_t stream) {
    (void)in_sizes; (void)n_in; (void)out_size; (void)ws_size;
    const float* feats = (const float*)d_in[0];   // [16,1024,768]
    const float* targ  = (const float*)d_in[1];   // [16,768,768]
    const float* W     = (const float*)d_in[2];   // [768,128]
    const float* bias  = (const float*)d_in[3];   // [128]

    char* ws = (char*)d_ws;
    unsigned short* xbf = (unsigned short*)(ws + 0);            // 16384x128 bf16 = 4 MB
    unsigned short* ybf = (unsigned short*)(ws + 4194304);      // 12288x128 bf16 = 3 MB
    unsigned short* Wt  = (unsigned short*)(ws + 7340032);      // 128x768 bf16
    unsigned short* SxyE = (unsigned short*)(ws + 7536640);     // 16x1024x1792 bf16 E
    unsigned short* SxxE = (unsigned short*)(ws + 66256896);    // 16x1024x2048 bf16 E
    unsigned short* SyyE = (unsigned short*)(ws + 133365760);   // 16x768x1536  bf16 E

    hipMemsetAsync(d_out, 0, sizeof(float), stream);
    // zero all E streams so pad cells (invalid j) are E=0 -> alpha=0 automatically
    hipMemsetAsync(ws + 7536640, 0, 163577856, stream);

    wtrans_kernel<<<384, 256, 0, stream>>>(W, Wt);
    proj_kernel<<<128, 256, 0, stream>>>(feats, Wt, bias, xbf);
    proj_kernel<<<96, 256, 0, stream>>>(targ, Wt, bias, ybf);

    gram_kernel<<<dim3(8, 6, 16), 256, 0, stream>>>(xbf, ybf, SxyE, 1024,  768, 1792);
    gram_kernel<<<dim3(8, 8, 16), 256, 0, stream>>>(xbf, xbf, SxxE, 1024, 1024, 2048);
    gram_kernel<<<dim3(6, 6, 16), 256, 0, stream>>>(ybf, ybf, SyyE,  768,  768, 1536);

    // 4-wave cooperative DP: dynamic LDS = (NWAVE-1)*(BPAD*8 + SLEN*4), max (Sxx) = 32640 B
    dp_kernel<<<dim3(16, 3), 256, 32768, stream>>>(SxyE, SxxE, SyyE, (float*)d_out);
}

// Round 5
// 530.488 us; speedup vs baseline: 1.3511x; 1.0160x over previous
//
#include <hip/hip_runtime.h>

typedef float  f4  __attribute__((ext_vector_type(4)));
typedef __bf16 bf8 __attribute__((ext_vector_type(8)));
typedef short  s8  __attribute__((ext_vector_type(8)));
typedef int    i2  __attribute__((ext_vector_type(2)));
typedef double d2v __attribute__((ext_vector_type(2)));

__device__ inline unsigned short f2bf_bits(float f) {
    unsigned u = __float_as_uint(f);
    u += 0x7fffu + ((u >> 16) & 1u);   // RNE to bf16
    return (unsigned short)(u >> 16);
}

// ---------------- W transpose + bf16 convert: Wt[n][k] = bf16(W[k][n]) ----------------
__global__ __launch_bounds__(256) void wtrans_kernel(const float* __restrict__ W,
                                                     unsigned short* __restrict__ Wt) {
    int idx = blockIdx.x * 256 + threadIdx.x;
    if (idx < 768 * 128) {
        int k = idx >> 7, n = idx & 127;
        Wt[n * 768 + k] = f2bf_bits(W[idx]);
    }
}

// ---------------- projection: Out = bf16(l2norm(In @ W + b)), 128-row tiles ----------------
__global__ __launch_bounds__(256) void proj_kernel(const float* __restrict__ In,
                                                   const unsigned short* __restrict__ Wt,
                                                   const float* __restrict__ bias,
                                                   unsigned short* __restrict__ Out) {
    int tid = threadIdx.x;
    int wave = tid >> 6, lane = tid & 63;
    int quad = lane >> 4, rq = lane & 15;
    int rh = (wave >> 1) * 64, ch = (wave & 1) * 64;
    long rowBase = (long)blockIdx.x * 128 + rh;

    f4 acc[4][4];
#pragma unroll
    for (int a = 0; a < 4; ++a)
#pragma unroll
        for (int b = 0; b < 4; ++b) acc[a][b] = 0.0f;

    for (int kc = 0; kc < 24; ++kc) {
        int k0 = kc * 32 + quad * 8;
        bf8 af[4], bfr[4];
#pragma unroll
        for (int t = 0; t < 4; ++t) {
            const float* ap = In + (rowBase + t * 16 + rq) * 768 + k0;
            f4 u0 = *(const f4*)ap;
            f4 u1 = *(const f4*)(ap + 4);
            s8 tmp;
            tmp[0] = (short)f2bf_bits(u0[0]); tmp[1] = (short)f2bf_bits(u0[1]);
            tmp[2] = (short)f2bf_bits(u0[2]); tmp[3] = (short)f2bf_bits(u0[3]);
            tmp[4] = (short)f2bf_bits(u1[0]); tmp[5] = (short)f2bf_bits(u1[1]);
            tmp[6] = (short)f2bf_bits(u1[2]); tmp[7] = (short)f2bf_bits(u1[3]);
            af[t] = __builtin_bit_cast(bf8, tmp);
            bfr[t] = *(const bf8*)(const void*)(Wt + (ch + t * 16 + rq) * 768 + k0);
        }
#pragma unroll
        for (int ti = 0; ti < 4; ++ti)
#pragma unroll
            for (int tj = 0; tj < 4; ++tj)
                acc[ti][tj] = __builtin_amdgcn_mfma_f32_16x16x32_bf16(af[ti], bfr[tj], acc[ti][tj], 0, 0, 0);
    }

    __shared__ float ssq[128];
    if (tid < 128) ssq[tid] = 0.f;
    __syncthreads();

    float b4[4];
#pragma unroll
    for (int tj = 0; tj < 4; ++tj) b4[tj] = bias[ch + tj * 16 + rq];

#pragma unroll
    for (int ti = 0; ti < 4; ++ti)
#pragma unroll
        for (int r = 0; r < 4; ++r) {
            float p = 0.f;
#pragma unroll
            for (int tj = 0; tj < 4; ++tj) {
                float z = acc[ti][tj][r] + b4[tj];
                p += z * z;
            }
            atomicAdd(&ssq[rh + ti * 16 + quad * 4 + r], p);
        }
    __syncthreads();

#pragma unroll
    for (int ti = 0; ti < 4; ++ti)
#pragma unroll
        for (int r = 0; r < 4; ++r) {
            int rowL = rh + ti * 16 + quad * 4 + r;
            float rn = rsqrtf(ssq[rowL]);
#pragma unroll
            for (int tj = 0; tj < 4; ++tj) {
                float z = (acc[ti][tj][r] + b4[tj]) * rn;
                Out[((long)blockIdx.x * 128 + rowL) * 128 + ch + tj * 16 + rq] = f2bf_bits(z);
            }
        }
}

// ------- gram: E[b][i][d=i+j] = bf16(exp((2*dot-2)*10)) = exp(-D/gamma), diagonal stream -------
__global__ __launch_bounds__(256) void gram_kernel(const unsigned short* __restrict__ X,
                                                   const unsigned short* __restrict__ Y,
                                                   unsigned short* __restrict__ S,
                                                   int N, int M, int Nd8) {
    int b = blockIdx.z;
    long i0 = (long)blockIdx.x * 128, j0 = (long)blockIdx.y * 128;
    const unsigned short* Xb = X + (long)b * N * 128;
    const unsigned short* Yb = Y + (long)b * M * 128;
    unsigned short* Sb = S + (long)b * N * Nd8;
    int tid = threadIdx.x, wave = tid >> 6, lane = tid & 63;
    int quad = lane >> 4, rq = lane & 15;
    int rh = (wave >> 1) * 64, ch = (wave & 1) * 64;

    f4 acc[4][4];
#pragma unroll
    for (int a = 0; a < 4; ++a)
#pragma unroll
        for (int c = 0; c < 4; ++c) acc[a][c] = 0.0f;

#pragma unroll
    for (int kc = 0; kc < 4; ++kc) {
        int k0 = kc * 32 + quad * 8;
        bf8 af[4], bfr[4];
#pragma unroll
        for (int t = 0; t < 4; ++t) {
            af[t]  = *(const bf8*)(const void*)(Xb + (i0 + rh + t * 16 + rq) * 128 + k0);
            bfr[t] = *(const bf8*)(const void*)(Yb + (j0 + ch + t * 16 + rq) * 128 + k0);
        }
#pragma unroll
        for (int ti = 0; ti < 4; ++ti)
#pragma unroll
            for (int tj = 0; tj < 4; ++tj)
                acc[ti][tj] = __builtin_amdgcn_mfma_f32_16x16x32_bf16(af[ti], bfr[tj], acc[ti][tj], 0, 0, 0);
    }

#pragma unroll
    for (int ti = 0; ti < 4; ++ti)
#pragma unroll
        for (int r = 0; r < 4; ++r) {
            long gi = i0 + rh + ti * 16 + quad * 4 + r;
#pragma unroll
            for (int tj = 0; tj < 4; ++tj) {
                long gj = j0 + ch + tj * 16 + rq;
                float Ev = __expf(20.0f * acc[ti][tj][r] - 20.0f);
                Sb[gi * Nd8 + gi + gj] = f2bf_bits(Ev);
            }
        }
}

// ---------------- soft-DTW alpha-space DP (fp64) ----------------
// 8-wave (Sxy/Sxx) / 6-wave (Syy) cooperative wavefront, K=2 rows/lane. EXACT R3 relay
// protocol (harness-verified): full-length boundary buffers, 2 frame slots per chunk,
// 2 DRESC per chunk, per-chunk unified pre-anchor (first-contact adoption + injection
// overflow guarantee). Only the wave decomposition changed vs R3 (K 4->2, NWAVE up).
__device__ inline double wshr1_d(double x) {  // lane l <- lane l-1, lane 0 <- 0
    i2 v = __builtin_bit_cast(i2, x);
    v.x = __builtin_amdgcn_update_dpp(0, v.x, 0x138, 0xf, 0xf, false);
    v.y = __builtin_amdgcn_update_dpp(0, v.y, 0x138, 0xf, 0xf, false);
    return __builtin_bit_cast(double, v);
}
#define DPPMAXI(x, ctrl) max((x), __builtin_amdgcn_update_dpp(0, (x), (ctrl), 0xf, 0xf, false))
__device__ inline int redmax64_i(int x) {   // full max in lane 63 (patterns >= 0)
    x = DPPMAXI(x, 0x111);  // row_shr:1
    x = DPPMAXI(x, 0x112);  // row_shr:2
    x = DPPMAXI(x, 0x114);  // row_shr:4
    x = DPPMAXI(x, 0x118);  // row_shr:8
    x = DPPMAXI(x, 0x142);  // row_bcast15
    x = DPPMAXI(x, 0x143);  // row_bcast31
    return x;
}
__device__ inline int hiw(double x) { return __builtin_bit_cast(i2, x).y; }

// K rows/lane PER WAVE; NWAVE active waves; rows per wave NW = 64*K; N = NWAVE*NW.
// Block may have more waves than NWAVE (idle waves only barrier).
template<int K, int N, int M, int ND8, int NWAVE>
static __device__ __attribute__((always_inline))
void dp_impl(const unsigned short* __restrict__ E, float wscale,
             float* __restrict__ out, char* __restrict__ smem) {
    constexpr int NW    = K * 64;              // rows handled by one wave
    constexpr int BLEN  = NW + M - 1;          // local diag count (odd for our shapes)
    constexpr int NCH   = (BLEN + 15) / 16;    // 16-step chunks per wave
    constexpr int BPAD  = NCH * 16;            // padded boundary buffer length
    constexpr int SLEN  = BPAD / 8;            // scale slots (one per 8-step half-group)
    constexpr int LAG   = NW / 16 + 1;         // chunk lag between adjacent waves
    constexpr int ROUNDS = (NWAVE - 1) * LAG + NCH;

    const int tid  = threadIdx.x;
    const int lane = tid & 63;
    const int w    = tid >> 6;                 // wave id = row-block id

    double* bvAll = (double*)smem;                                  // (NWAVE-1) x BPAD
    int*    scAll = (int*)(smem + (size_t)(NWAVE - 1) * BPAD * 8);  // (NWAVE-1) x SLEN

    const char* Eb = (const char*)(E + (long)blockIdx.x * N * ND8);
    unsigned off[K];
    uint4 eA[K], eB[K];
    double vA[K], vB[K];
#pragma unroll
    for (int r = 0; r < K; ++r) {
        // wave w's rows start at w*NW; its local diag 0 is global diag w*NW
        off[r] = (unsigned)((((long)(w * NW + K * lane + r)) * ND8 + (long)(w * NW)) * 2);
        vA[r] = 0.0; vB[r] = 0.0;
    }
    int ls = 0;                               // accumulated log2 scale (wave-uniform)

#define EGETV(EQ, PH) __uint_as_float(((PH) & 1) ? ((&(EQ).x)[(PH) >> 1] & 0xffff0000u) \
                                                 : ((&(EQ).x)[(PH) >> 1] << 16))
    // one anti-diagonal: writes W (held A[d-2], becomes A[d]), reads P1 (= A[d-1]).
    // S2/S1 inject the upstream-wave boundary (diag / above) into lane 0; exact +0.0 elsewhere.
#define DSTEP(W, P1, EB_, PH, S2, S1) do { \
        double b1 = wshr1_d(P1[K - 1]) + (S1); \
        double b2 = wshr1_d(W[K - 1]) + (S2); \
        double p2 = b2, p1m = b1; \
        _Pragma("unroll") \
        for (int r = 0; r < K; ++r) { \
            double told = W[r]; double c1 = P1[r]; \
            double Ed = (double)EGETV(EB_[r], PH); \
            W[r] = Ed * (p2 + p1m + c1); \
            p2 = told; p1m = c1; \
        } } while (0)

    // pow2 rescale of BOTH live diagonals, anchor 2^870 (biased 1893). Headroom above
    // anchor 2^154 = e^107 covers the e^40 boundary-coupling bound; depth below anchor
    // (870+1074) bits = 134.7 cost units, so nothing reachable is flushed.
#define DRESC(W, P1) do { \
        int hm = hiw(W[0]) > hiw(P1[0]) ? hiw(W[0]) : hiw(P1[0]); \
        _Pragma("unroll") \
        for (int r = 1; r < K; ++r) { \
            int h1 = hiw(W[r]), h2 = hiw(P1[r]); \
            if (h1 > hm) hm = h1; if (h2 > hm) hm = h2; } \
        hm = redmax64_i(hm); \
        int hb = __builtin_amdgcn_readlane(hm, 63); \
        if (hb > 0) { \
            int eraw2 = (hb >> 20) & 0x7ff; \
            int sh = 1893 - eraw2;                     /* target exponent 2^870 */ \
            sh = (sh > 1020) ? 1020 : ((sh < -1020) ? -1020 : sh); \
            i2 fb; fb.x = 0; fb.y = (1023 + sh) << 20; \
            double f = __builtin_bit_cast(double, fb); \
            ls += sh; \
            _Pragma("unroll") \
            for (int r = 0; r < K; ++r) { W[r] *= f; P1[r] *= f; } \
        } } while (0)

    for (int round = 0; round < ROUNDS; ++round) {
        const int c = round - w * LAG;         // this wave's chunk index (wave-uniform)
        if (w < NWAVE && c >= 0 && c < NCH) {
            // ---- boundary raw reads (broadcast, conflict-free). Entry g holds upstream
            // bottom-row alpha at column j' = g-(NW-1); step s uses entries gb+s (diag) and
            // gb+s+1 (above). NW ≡ 0 mod 8 so gb ≡ 6 mod 8: scale-slot offsets are static.
            // Clamped reads (beyond BPAD) correspond to columns >= M and are masked below.
            double raw[17]; int sc3[3];
            const int gb = NW - 2 + 16 * c;
            if (w > 0) {
                const double* bvR = bvAll + (size_t)(w - 1) * BPAD;
                const int*    scR = scAll + (w - 1) * SLEN;
#pragma unroll
                for (int i = 0; i < 8; ++i) {
                    int idx = gb + 2 * i; if (idx > BPAD - 2) idx = BPAD - 2;
                    d2v p = *(const d2v*)(bvR + idx);
                    raw[2 * i] = p.x; raw[2 * i + 1] = p.y;
                }
                int idx16 = gb + 16; if (idx16 > BPAD - 1) idx16 = BPAD - 1;
                raw[16] = bvR[idx16];
#pragma unroll
                for (int i = 0; i < 3; ++i) {
                    int s = (gb >> 3) + i; if (s > SLEN - 1) s = SLEN - 1;
                    sc3[i] = scR[s];
                }

                // ---- unified pre-anchor: fold own field max with incoming injection
                // magnitudes (reader frame), target 2^870. If own field is zero (first
                // contact), set ls directly (no multiply, unbounded jump safe on zeros).
                int hm0 = hiw(vA[0]) > hiw(vB[0]) ? hiw(vA[0]) : hiw(vB[0]);
#pragma unroll
                for (int r = 1; r < K; ++r) {
                    int h1 = hiw(vA[r]), h2 = hiw(vB[r]);
                    if (h1 > hm0) hm0 = h1; if (h2 > hm0) hm0 = h2;
                }
                hm0 = redmax64_i(hm0);
                int hbOwn = __builtin_amdgcn_readlane(hm0, 63);
                int ownEb = (hbOwn > 0) ? (hbOwn >> 20) : -1048576;
                int injEb = -1048576;
#pragma unroll
                for (int i = 0; i <= 16; ++i) {
                    int jp = 16 * c + i - 1;                 // column of raw[i]
                    int er = hiw(raw[i]) >> 20;              // biased exp (values >= 0)
                    int cand = er + (ls - sc3[(6 + i) >> 3]);
                    if (jp >= 0 && jp < M && er > 0 && cand > injEb) injEb = cand;
                }
                int MB = ownEb > injEb ? ownEb : injEb;
                if (MB > -1048576) {
                    int sh = 1893 - MB;
                    if (hbOwn > 0) {
                        sh = (sh > 1020) ? 1020 : ((sh < -1020) ? -1020 : sh);
                        i2 fb; fb.x = 0; fb.y = (1023 + sh) << 20;
                        double f = __builtin_bit_cast(double, fb);
#pragma unroll
                        for (int r = 0; r < K; ++r) { vA[r] *= f; vB[r] *= f; }
                    }
                    ls += sh;
                }
            }
            // ---- E loads: chunk = 16 diag entries = 32 bytes per row
            if (c == 0) {
#pragma unroll
                for (int r = 0; r < K; ++r) eA[r] = *(const uint4*)(const void*)(Eb + off[r]);
            }
#pragma unroll
            for (int r = 0; r < K; ++r) eB[r] = *(const uint4*)(const void*)(Eb + (off[r] + 16));

            // ---- injections for steps 0-7: stored_r = raw * 2^(ls_r - ls_w)
            double ca[9];
            if (w > 0) {
#pragma unroll
                for (int i = 0; i <= 8; ++i) {
                    int jp = 16 * c - 1 + i;
                    double v = fmin(ldexp(raw[i], ls - sc3[(6 + i) >> 3]), 8.9e307);
                    ca[i] = (lane == 0 && jp >= 0 && jp < M) ? v : 0.0;
                }
            } else {
#pragma unroll
                for (int i = 0; i <= 8; ++i) ca[i] = 0.0;
                if (c == 0 && lane == 0) ca[0] = 1.0;  // alpha[-1][-1] = 1 seed
            }

            double bb[8];                              // bottom-row collect for relay
            DSTEP(vA, vB, eA, 0, ca[0], ca[1]); bb[0] = vA[K - 1];
            DSTEP(vB, vA, eA, 1, ca[1], ca[2]); bb[1] = vB[K - 1];
            DSTEP(vA, vB, eA, 2, ca[2], ca[3]); bb[2] = vA[K - 1];
            DSTEP(vB, vA, eA, 3, ca[3], ca[4]); bb[3] = vB[K - 1];
            DSTEP(vA, vB, eA, 4, ca[4], ca[5]); bb[4] = vA[K - 1];
            DSTEP(vB, vA, eA, 5, ca[5], ca[6]); bb[5] = vB[K - 1];
            DSTEP(vA, vB, eA, 6, ca[6], ca[7]); bb[6] = vA[K - 1];
            DSTEP(vB, vA, eA, 7, ca[7], ca[8]); bb[7] = vB[K - 1];
            if (w < NWAVE - 1 && lane == 63) {
                double* bvW = bvAll + (size_t)w * BPAD;
                int*    scW = scAll + w * SLEN;
#pragma unroll
                for (int i = 0; i < 4; ++i) {
                    d2v p; p.x = bb[2 * i]; p.y = bb[2 * i + 1];
                    *(d2v*)(bvW + 16 * c + 2 * i) = p;
                }
                scW[2 * c] = ls;                       // frame of the 8 values just written
            }
            DRESC(vB, vA);
            if (c + 1 < NCH) {
#pragma unroll
                for (int r = 0; r < K; ++r) eA[r] = *(const uint4*)(const void*)(Eb + (off[r] + 32));
            }

            // ---- injections for steps 8-15 (post-DRESC ls: current frame)
            double cb[9];
            if (w > 0) {
#pragma unroll
                for (int i = 0; i <= 8; ++i) {
                    int jp = 16 * c + 7 + i;
                    double v = fmin(ldexp(raw[8 + i], ls - sc3[(14 + i) >> 3]), 8.9e307);
                    cb[i] = (lane == 0 && jp < M) ? v : 0.0;
                }
            } else {
#pragma unroll
                for (int i = 0; i <= 8; ++i) cb[i] = 0.0;
            }

            DSTEP(vA, vB, eB, 0, cb[0], cb[1]); bb[0] = vA[K - 1];
            DSTEP(vB, vA, eB, 1, cb[1], cb[2]); bb[1] = vB[K - 1];
            DSTEP(vA, vB, eB, 2, cb[2], cb[3]); bb[2] = vA[K - 1];
            DSTEP(vB, vA, eB, 3, cb[3], cb[4]); bb[3] = vB[K - 1];
            DSTEP(vA, vB, eB, 4, cb[4], cb[5]); bb[4] = vA[K - 1];
            DSTEP(vB, vA, eB, 5, cb[5], cb[6]); bb[5] = vB[K - 1];
            DSTEP(vA, vB, eB, 6, cb[6], cb[7]); bb[6] = vA[K - 1];
            DSTEP(vB, vA, eB, 7, cb[7], cb[8]); bb[7] = vB[K - 1];
            if (w < NWAVE - 1 && lane == 63) {
                double* bvW = bvAll + (size_t)w * BPAD;
                int*    scW = scAll + w * SLEN;
#pragma unroll
                for (int i = 0; i < 4; ++i) {
                    d2v p; p.x = bb[2 * i]; p.y = bb[2 * i + 1];
                    *(d2v*)(bvW + 16 * c + 8 + 2 * i) = p;
                }
                scW[2 * c + 1] = ls;
            }
            DRESC(vB, vA);
#pragma unroll
            for (int r = 0; r < K; ++r) off[r] += 32;
        }
        // publish this round's LDS writes, then sync. Raw s_barrier (no vmcnt drain):
        // the in-flight E prefetches survive across the barrier.
        asm volatile("s_waitcnt lgkmcnt(0)\n\ts_barrier" ::: "memory");
    }

    if (w == NWAVE - 1 && lane == 63) {
        // A[N-1][M-1] at last-wave local diag BLEN-1 (even -> vA), row N-1 = lane 63, r = K-1
        double v = vA[K - 1];
        i2 vb2 = __builtin_bit_cast(i2, v);
        int eraw = (vb2.y >> 20) & 0x7ff;
        int ex = eraw - 1022;                       // v = m * 2^ex, m in [0.5,1)
        i2 mb; mb.x = vb2.x; mb.y = (vb2.y & 0x000FFFFF) | (1022 << 20);
        float mf = (float)__builtin_bit_cast(double, mb);
        if (!(mf > 0.f)) mf = 0.5f;                 // guard (cannot happen if DP sane)
        double R = -0.1 * ((double)logf(mf) + (double)(ex - ls) * 0.6931471805599453);
        atomicAdd(out, wscale * (float)R);
    }
#undef DSTEP
#undef DRESC
#undef EGETV
}

__global__ __launch_bounds__(512) void dp_kernel(const unsigned short* __restrict__ Sxy,
                                                 const unsigned short* __restrict__ Sxx,
                                                 const unsigned short* __restrict__ Syy,
                                                 float* __restrict__ out) {
    // static LDS, max case = Sxx: 7 regions x (1152 dbl + 144 int) = 68544 B (<160 KiB HW max)
    __shared__ __attribute__((aligned(16))) char smem[68544];
    if (blockIdx.y == 0)      dp_impl<2, 1024,  768, 1792, 8>(Sxy,  1.0f / 28672.0f, out, smem);
    else if (blockIdx.y == 1) dp_impl<2, 1024, 1024, 2048, 8>(Sxx, -0.5f / 28672.0f, out, smem);
    else                      dp_impl<2,  768,  768, 1536, 6>(Syy, -0.5f / 28672.0f, out, smem);
}

// ---------------- host launcher ----------------
extern "C" void kernel_launch(void* const* d_in, const int* in_sizes, int n_in,
                              void* d_out, int out_size, void* d_ws, size_t ws_size,
                              hipStream_t stream) {
    (void)in_sizes; (void)n_in; (void)out_size; (void)ws_size;
    const float* feats = (const float*)d_in[0];   // [16,1024,768]
    const float* targ  = (const float*)d_in[1];   // [16,768,768]
    const float* W     = (const float*)d_in[2];   // [768,128]
    const float* bias  = (const float*)d_in[3];   // [128]

    char* ws = (char*)d_ws;
    unsigned short* xbf = (unsigned short*)(ws + 0);            // 16384x128 bf16 = 4 MB
    unsigned short* ybf = (unsigned short*)(ws + 4194304);      // 12288x128 bf16 = 3 MB
    unsigned short* Wt  = (unsigned short*)(ws + 7340032);      // 128x768 bf16
    unsigned short* SxyE = (unsigned short*)(ws + 7536640);     // 16x1024x1792 bf16 E
    unsigned short* SxxE = (unsigned short*)(ws + 66256896);    // 16x1024x2048 bf16 E
    unsigned short* SyyE = (unsigned short*)(ws + 133365760);   // 16x768x1536  bf16 E

    hipMemsetAsync(d_out, 0, sizeof(float), stream);
    // zero all E streams so pad cells (invalid j) are E=0 -> alpha=0 automatically
    hipMemsetAsync(ws + 7536640, 0, 163577856, stream);

    wtrans_kernel<<<384, 256, 0, stream>>>(W, Wt);
    proj_kernel<<<128, 256, 0, stream>>>(feats, Wt, bias, xbf);
    proj_kernel<<<96, 256, 0, stream>>>(targ, Wt, bias, ybf);

    gram_kernel<<<dim3(8, 6, 16), 256, 0, stream>>>(xbf, ybf, SxyE, 1024,  768, 1792);
    gram_kernel<<<dim3(8, 8, 16), 256, 0, stream>>>(xbf, xbf, SxxE, 1024, 1024, 2048);
    gram_kernel<<<dim3(6, 6, 16), 256, 0, stream>>>(ybf, ybf, SyyE,  768,  768, 1536);

    // 8-wave cooperative DP (Syy: 6 active + 2 idle waves), R3-verified relay protocol
    dp_kernel<<<dim3(16, 3), 512, 0, stream>>>(SxyE, SxxE, SyyE, (float*)d_out);
}

// Round 6
// 503.001 us; speedup vs baseline: 1.4249x; 1.0546x over previous
//
#include <hip/hip_runtime.h>

typedef float  f4  __attribute__((ext_vector_type(4)));
typedef __bf16 bf8 __attribute__((ext_vector_type(8)));
typedef short  s8  __attribute__((ext_vector_type(8)));
typedef int    i2  __attribute__((ext_vector_type(2)));
typedef double d2v __attribute__((ext_vector_type(2)));

__device__ inline unsigned short f2bf_bits(float f) {
    unsigned u = __float_as_uint(f);
    u += 0x7fffu + ((u >> 16) & 1u);   // RNE to bf16
    return (unsigned short)(u >> 16);
}

// ---------------- W transpose + bf16 convert: Wt[n][k] = bf16(W[k][n]) ----------------
__global__ __launch_bounds__(256) void wtrans_kernel(const float* __restrict__ W,
                                                     unsigned short* __restrict__ Wt) {
    int idx = blockIdx.x * 256 + threadIdx.x;
    if (idx < 768 * 128) {
        int k = idx >> 7, n = idx & 127;
        Wt[n * 768 + k] = f2bf_bits(W[idx]);
    }
}

// ---------------- projection: Out = bf16(l2norm(In @ W + b)), 128-row tiles ----------------
__global__ __launch_bounds__(256) void proj_kernel(const float* __restrict__ In,
                                                   const unsigned short* __restrict__ Wt,
                                                   const float* __restrict__ bias,
                                                   unsigned short* __restrict__ Out) {
    int tid = threadIdx.x;
    int wave = tid >> 6, lane = tid & 63;
    int quad = lane >> 4, rq = lane & 15;
    int rh = (wave >> 1) * 64, ch = (wave & 1) * 64;
    long rowBase = (long)blockIdx.x * 128 + rh;

    f4 acc[4][4];
#pragma unroll
    for (int a = 0; a < 4; ++a)
#pragma unroll
        for (int b = 0; b < 4; ++b) acc[a][b] = 0.0f;

    for (int kc = 0; kc < 24; ++kc) {
        int k0 = kc * 32 + quad * 8;
        bf8 af[4], bfr[4];
#pragma unroll
        for (int t = 0; t < 4; ++t) {
            const float* ap = In + (rowBase + t * 16 + rq) * 768 + k0;
            f4 u0 = *(const f4*)ap;
            f4 u1 = *(const f4*)(ap + 4);
            s8 tmp;
            tmp[0] = (short)f2bf_bits(u0[0]); tmp[1] = (short)f2bf_bits(u0[1]);
            tmp[2] = (short)f2bf_bits(u0[2]); tmp[3] = (short)f2bf_bits(u0[3]);
            tmp[4] = (short)f2bf_bits(u1[0]); tmp[5] = (short)f2bf_bits(u1[1]);
            tmp[6] = (short)f2bf_bits(u1[2]); tmp[7] = (short)f2bf_bits(u1[3]);
            af[t] = __builtin_bit_cast(bf8, tmp);
            bfr[t] = *(const bf8*)(const void*)(Wt + (ch + t * 16 + rq) * 768 + k0);
        }
#pragma unroll
        for (int ti = 0; ti < 4; ++ti)
#pragma unroll
            for (int tj = 0; tj < 4; ++tj)
                acc[ti][tj] = __builtin_amdgcn_mfma_f32_16x16x32_bf16(af[ti], bfr[tj], acc[ti][tj], 0, 0, 0);
    }

    __shared__ float ssq[128];
    if (tid < 128) ssq[tid] = 0.f;
    __syncthreads();

    float b4[4];
#pragma unroll
    for (int tj = 0; tj < 4; ++tj) b4[tj] = bias[ch + tj * 16 + rq];

#pragma unroll
    for (int ti = 0; ti < 4; ++ti)
#pragma unroll
        for (int r = 0; r < 4; ++r) {
            float p = 0.f;
#pragma unroll
            for (int tj = 0; tj < 4; ++tj) {
                float z = acc[ti][tj][r] + b4[tj];
                p += z * z;
            }
            atomicAdd(&ssq[rh + ti * 16 + quad * 4 + r], p);
        }
    __syncthreads();

#pragma unroll
    for (int ti = 0; ti < 4; ++ti)
#pragma unroll
        for (int r = 0; r < 4; ++r) {
            int rowL = rh + ti * 16 + quad * 4 + r;
            float rn = rsqrtf(ssq[rowL]);
#pragma unroll
            for (int tj = 0; tj < 4; ++tj) {
                float z = (acc[ti][tj][r] + b4[tj]) * rn;
                Out[((long)blockIdx.x * 128 + rowL) * 128 + ch + tj * 16 + rq] = f2bf_bits(z);
            }
        }
}

// ------- gram: E[b][i][d=i+j] = bf16(exp((2*dot-2)*10)) = exp(-D/gamma), diagonal stream -------
__global__ __launch_bounds__(256) void gram_kernel(const unsigned short* __restrict__ X,
                                                   const unsigned short* __restrict__ Y,
                                                   unsigned short* __restrict__ S,
                                                   int N, int M, int Nd8) {
    int b = blockIdx.z;
    long i0 = (long)blockIdx.x * 128, j0 = (long)blockIdx.y * 128;
    const unsigned short* Xb = X + (long)b * N * 128;
    const unsigned short* Yb = Y + (long)b * M * 128;
    unsigned short* Sb = S + (long)b * N * Nd8;
    int tid = threadIdx.x, wave = tid >> 6, lane = tid & 63;
    int quad = lane >> 4, rq = lane & 15;
    int rh = (wave >> 1) * 64, ch = (wave & 1) * 64;

    f4 acc[4][4];
#pragma unroll
    for (int a = 0; a < 4; ++a)
#pragma unroll
        for (int c = 0; c < 4; ++c) acc[a][c] = 0.0f;

#pragma unroll
    for (int kc = 0; kc < 4; ++kc) {
        int k0 = kc * 32 + quad * 8;
        bf8 af[4], bfr[4];
#pragma unroll
        for (int t = 0; t < 4; ++t) {
            af[t]  = *(const bf8*)(const void*)(Xb + (i0 + rh + t * 16 + rq) * 128 + k0);
            bfr[t] = *(const bf8*)(const void*)(Yb + (j0 + ch + t * 16 + rq) * 128 + k0);
        }
#pragma unroll
        for (int ti = 0; ti < 4; ++ti)
#pragma unroll
            for (int tj = 0; tj < 4; ++tj)
                acc[ti][tj] = __builtin_amdgcn_mfma_f32_16x16x32_bf16(af[ti], bfr[tj], acc[ti][tj], 0, 0, 0);
    }

#pragma unroll
    for (int ti = 0; ti < 4; ++ti)
#pragma unroll
        for (int r = 0; r < 4; ++r) {
            long gi = i0 + rh + ti * 16 + quad * 4 + r;
#pragma unroll
            for (int tj = 0; tj < 4; ++tj) {
                long gj = j0 + ch + tj * 16 + rq;
                float Ev = __expf(20.0f * acc[ti][tj][r] - 20.0f);
                Sb[gi * Nd8 + gi + gj] = f2bf_bits(Ev);
            }
        }
}

// ---------------- soft-DTW alpha-space DP (fp64) ----------------
// 8-wave (Sxy/Sxx) / 6-wave (Syy) cooperative wavefront, K=2 rows/lane.
// CHANGE vs R5 (harness-verified): 32-step chunks (4 groups of 8 DSTEPs per round)
// -> round count ~halves (Sxx 135->71), amortizing the K-independent per-round fixed
// cost (barrier, LDS boundary read, pre-anchor, DRESC chains, E vmcnt wait) that R5
// proved dominant. Relay semantics unchanged: full-length buffers, one scale slot per
// 8 boundary entries (written per group), unified pre-anchor, DRESC every 16 steps.
__device__ inline double wshr1_d(double x) {  // lane l <- lane l-1, lane 0 <- 0
    i2 v = __builtin_bit_cast(i2, x);
    v.x = __builtin_amdgcn_update_dpp(0, v.x, 0x138, 0xf, 0xf, false);
    v.y = __builtin_amdgcn_update_dpp(0, v.y, 0x138, 0xf, 0xf, false);
    return __builtin_bit_cast(double, v);
}
#define DPPMAXI(x, ctrl) max((x), __builtin_amdgcn_update_dpp(0, (x), (ctrl), 0xf, 0xf, false))
__device__ inline int redmax64_i(int x) {   // full max in lane 63 (patterns >= 0)
    x = DPPMAXI(x, 0x111);  // row_shr:1
    x = DPPMAXI(x, 0x112);  // row_shr:2
    x = DPPMAXI(x, 0x114);  // row_shr:4
    x = DPPMAXI(x, 0x118);  // row_shr:8
    x = DPPMAXI(x, 0x142);  // row_bcast15
    x = DPPMAXI(x, 0x143);  // row_bcast31
    return x;
}
__device__ inline int hiw(double x) { return __builtin_bit_cast(i2, x).y; }

// K rows/lane PER WAVE; NWAVE active waves; rows per wave NW = 64*K; N = NWAVE*NW.
template<int K, int N, int M, int ND8, int NWAVE>
static __device__ __attribute__((always_inline))
void dp_impl(const unsigned short* __restrict__ E, float wscale,
             float* __restrict__ out, char* __restrict__ smem) {
    constexpr int NW    = K * 64;              // rows handled by one wave
    constexpr int BLEN  = NW + M - 1;          // local diag count (odd; BLEN+1 ≡ 0 mod 32)
    constexpr int NCH   = (BLEN + 31) / 32;    // 32-step chunks per wave
    constexpr int BPAD  = NCH * 32;            // = BLEN+1 for all our shapes (1 pad step)
    constexpr int SLEN  = BPAD / 8;            // scale slots (one per 8 boundary entries)
    constexpr int LAG   = NW / 32 + 1;         // chunk lag between adjacent waves
    constexpr int ROUNDS = (NWAVE - 1) * LAG + NCH;

    const int tid  = threadIdx.x;
    const int lane = tid & 63;
    const int w    = tid >> 6;                 // wave id = row-block id

    double* bvAll = (double*)smem;                                  // (NWAVE-1) x BPAD
    int*    scAll = (int*)(smem + (size_t)(NWAVE - 1) * BPAD * 8);  // (NWAVE-1) x SLEN

    const char* Eb = (const char*)(E + (long)blockIdx.x * N * ND8);
    unsigned off[K];
    uint4 eA[K], eB[K], eC[K], eD[K];
    double vA[K], vB[K];
#pragma unroll
    for (int r = 0; r < K; ++r) {
        off[r] = (unsigned)((((long)(w * NW + K * lane + r)) * ND8 + (long)(w * NW)) * 2);
        vA[r] = 0.0; vB[r] = 0.0;
    }
    int ls = 0;                               // accumulated log2 scale (wave-uniform)

#define EGETV(EQ, PH) __uint_as_float(((PH) & 1) ? ((&(EQ).x)[(PH) >> 1] & 0xffff0000u) \
                                                 : ((&(EQ).x)[(PH) >> 1] << 16))
#define DSTEP(W, P1, EB_, PH, S2, S1) do { \
        double b1 = wshr1_d(P1[K - 1]) + (S1); \
        double b2 = wshr1_d(W[K - 1]) + (S2); \
        double p2 = b2, p1m = b1; \
        _Pragma("unroll") \
        for (int r = 0; r < K; ++r) { \
            double told = W[r]; double c1 = P1[r]; \
            double Ed = (double)EGETV(EB_[r], PH); \
            W[r] = Ed * (p2 + p1m + c1); \
            p2 = told; p1m = c1; \
        } } while (0)

    // pow2 rescale of BOTH live diagonals, anchor 2^870 (biased 1893), every 16 steps.
    // Growth bound between DRESCs: 3^16 * e^40 headroom < 2^1024; decay floor
    // 2^(870-923) >> denormal.
#define DRESC(W, P1) do { \
        int hm = hiw(W[0]) > hiw(P1[0]) ? hiw(W[0]) : hiw(P1[0]); \
        _Pragma("unroll") \
        for (int r = 1; r < K; ++r) { \
            int h1 = hiw(W[r]), h2 = hiw(P1[r]); \
            if (h1 > hm) hm = h1; if (h2 > hm) hm = h2; } \
        hm = redmax64_i(hm); \
        int hb = __builtin_amdgcn_readlane(hm, 63); \
        if (hb > 0) { \
            int eraw2 = (hb >> 20) & 0x7ff; \
            int sh = 1893 - eraw2; \
            sh = (sh > 1020) ? 1020 : ((sh < -1020) ? -1020 : sh); \
            i2 fb; fb.x = 0; fb.y = (1023 + sh) << 20; \
            double f = __builtin_bit_cast(double, fb); \
            ls += sh; \
            _Pragma("unroll") \
            for (int r = 0; r < K; ++r) { W[r] *= f; P1[r] *= f; } \
        } } while (0)

    // one 8-step group: injections (group frame = current ls), 8 DSTEPs, relay write.
    // Entry g = NW-2+32c+s pairs with step s; column jp(g) = g-(NW-1). Slot of entry
    // 8g'+i is g' ; (6+8G+i)>>3 = G + ((6+i)>>3) since 6+i<16.
#define GROUP(EX, G) do { \
        double cj[9]; \
        if (w > 0) { \
            _Pragma("unroll") \
            for (int i = 0; i <= 8; ++i) { \
                int jp = 32 * c + 8 * (G) - 1 + i; \
                double v = fmin(ldexp(raw[8 * (G) + i], ls - sc5[(G) + ((6 + i) >> 3)]), 8.9e307); \
                cj[i] = (lane == 0 && jp >= 0 && jp < M) ? v : 0.0; \
            } \
        } else { \
            _Pragma("unroll") \
            for (int i = 0; i <= 8; ++i) cj[i] = 0.0; \
            if ((G) == 0 && c == 0 && lane == 0) cj[0] = 1.0;  /* alpha[-1][-1]=1 seed */ \
        } \
        double bb[8]; \
        DSTEP(vA, vB, EX, 0, cj[0], cj[1]); bb[0] = vA[K - 1]; \
        DSTEP(vB, vA, EX, 1, cj[1], cj[2]); bb[1] = vB[K - 1]; \
        DSTEP(vA, vB, EX, 2, cj[2], cj[3]); bb[2] = vA[K - 1]; \
        DSTEP(vB, vA, EX, 3, cj[3], cj[4]); bb[3] = vB[K - 1]; \
        DSTEP(vA, vB, EX, 4, cj[4], cj[5]); bb[4] = vA[K - 1]; \
        DSTEP(vB, vA, EX, 5, cj[5], cj[6]); bb[5] = vB[K - 1]; \
        DSTEP(vA, vB, EX, 6, cj[6], cj[7]); bb[6] = vA[K - 1]; \
        DSTEP(vB, vA, EX, 7, cj[7], cj[8]); bb[7] = vB[K - 1]; \
        if (w < NWAVE - 1 && lane == 63) { \
            double* bvW = bvAll + (size_t)w * BPAD; \
            int*    scW = scAll + w * SLEN; \
            _Pragma("unroll") \
            for (int i = 0; i < 4; ++i) { \
                d2v p; p.x = bb[2 * i]; p.y = bb[2 * i + 1]; \
                *(d2v*)(bvW + 32 * c + 8 * (G) + 2 * i) = p; \
            } \
            scW[4 * c + (G)] = ls; \
        } } while (0)

    for (int round = 0; round < ROUNDS; ++round) {
        const int c = round - w * LAG;         // this wave's chunk index (wave-uniform)
        if (w < NWAVE && c >= 0 && c < NCH) {
            // ---- boundary raw reads: 33 entries gb..gb+32, gb = NW-2+32c (even, ≡6 mod 8).
            // Clamped reads map to columns >= M and are masked in GROUP.
            double raw[33]; int sc5[5];
            const int gb = NW - 2 + 32 * c;
            if (w > 0) {
                const double* bvR = bvAll + (size_t)(w - 1) * BPAD;
                const int*    scR = scAll + (w - 1) * SLEN;
#pragma unroll
                for (int i = 0; i < 16; ++i) {
                    int idx = gb + 2 * i; if (idx > BPAD - 2) idx = BPAD - 2;
                    d2v p = *(const d2v*)(bvR + idx);
                    raw[2 * i] = p.x; raw[2 * i + 1] = p.y;
                }
                int idx32 = gb + 32; if (idx32 > BPAD - 1) idx32 = BPAD - 1;
                raw[32] = bvR[idx32];
#pragma unroll
                for (int j = 0; j < 5; ++j) {
                    int s = (gb >> 3) + j; if (s > SLEN - 1) s = SLEN - 1;
                    sc5[j] = scR[s];
                }

                // ---- unified pre-anchor: fold own-field max with incoming injection
                // magnitudes (reader frame), target 2^870. Own field zero (first contact)
                // -> direct ls jump (no multiply; zeros unaffected).
                int hm0 = hiw(vA[0]) > hiw(vB[0]) ? hiw(vA[0]) : hiw(vB[0]);
#pragma unroll
                for (int r = 1; r < K; ++r) {
                    int h1 = hiw(vA[r]), h2 = hiw(vB[r]);
                    if (h1 > hm0) hm0 = h1; if (h2 > hm0) hm0 = h2;
                }
                hm0 = redmax64_i(hm0);
                int hbOwn = __builtin_amdgcn_readlane(hm0, 63);
                int ownEb = (hbOwn > 0) ? (hbOwn >> 20) : -1048576;
                int injEb = -1048576;
#pragma unroll
                for (int i = 0; i <= 32; ++i) {
                    int jp = 32 * c + i - 1;                 // column of raw[i]
                    int er = hiw(raw[i]) >> 20;              // biased exp (values >= 0)
                    int cand = er + (ls - sc5[(6 + i) >> 3]);
                    if (jp >= 0 && jp < M && er > 0 && cand > injEb) injEb = cand;
                }
                int MB = ownEb > injEb ? ownEb : injEb;
                if (MB > -1048576) {
                    int sh = 1893 - MB;
                    if (hbOwn > 0) {
                        sh = (sh > 1020) ? 1020 : ((sh < -1020) ? -1020 : sh);
                        i2 fb; fb.x = 0; fb.y = (1023 + sh) << 20;
                        double f = __builtin_bit_cast(double, fb);
#pragma unroll
                        for (int r = 0; r < K; ++r) { vA[r] *= f; vB[r] *= f; }
                    }
                    ls += sh;
                }
            }
            // ---- E loads: chunk = 32 diag entries = 64 bytes per row (4x uint4)
            if (c == 0) {
#pragma unroll
                for (int r = 0; r < K; ++r) eA[r] = *(const uint4*)(const void*)(Eb + off[r]);
            }
#pragma unroll
            for (int r = 0; r < K; ++r) {
                eB[r] = *(const uint4*)(const void*)(Eb + (off[r] + 16));
                eC[r] = *(const uint4*)(const void*)(Eb + (off[r] + 32));
                eD[r] = *(const uint4*)(const void*)(Eb + (off[r] + 48));
            }

            GROUP(eA, 0);
            GROUP(eB, 1);
            DRESC(vB, vA);
            if (c + 1 < NCH) {
#pragma unroll
                for (int r = 0; r < K; ++r) eA[r] = *(const uint4*)(const void*)(Eb + (off[r] + 64));
            }
            GROUP(eC, 2);
            GROUP(eD, 3);
            DRESC(vB, vA);
#pragma unroll
            for (int r = 0; r < K; ++r) off[r] += 64;
        }
        // publish this round's LDS writes, then sync. Raw s_barrier (no vmcnt drain):
        // in-flight E prefetches survive across the barrier.
        asm volatile("s_waitcnt lgkmcnt(0)\n\ts_barrier" ::: "memory");
    }

    if (w == NWAVE - 1 && lane == 63) {
        // A[N-1][M-1] at last-wave local diag BLEN-1 (even -> vA); the single pad step
        // (odd) scribbles vB only. Row N-1 = lane 63, r = K-1.
        double v = vA[K - 1];
        i2 vb2 = __builtin_bit_cast(i2, v);
        int eraw = (vb2.y >> 20) & 0x7ff;
        int ex = eraw - 1022;                       // v = m * 2^ex, m in [0.5,1)
        i2 mb; mb.x = vb2.x; mb.y = (vb2.y & 0x000FFFFF) | (1022 << 20);
        float mf = (float)__builtin_bit_cast(double, mb);
        if (!(mf > 0.f)) mf = 0.5f;                 // guard (cannot happen if DP sane)
        double R = -0.1 * ((double)logf(mf) + (double)(ex - ls) * 0.6931471805599453);
        atomicAdd(out, wscale * (float)R);
    }
#undef DSTEP
#undef DRESC
#undef GROUP
#undef EGETV
}

__global__ __launch_bounds__(512) void dp_kernel(const unsigned short* __restrict__ Sxy,
                                                 const unsigned short* __restrict__ Sxx,
                                                 const unsigned short* __restrict__ Syy,
                                                 float* __restrict__ out) {
    // static LDS, max case = Sxx: 7 regions x (1152 dbl + 144 int) = 68544 B
    __shared__ __attribute__((aligned(16))) char smem[68544];
    if (blockIdx.y == 0)      dp_impl<2, 1024,  768, 1792, 8>(Sxy,  1.0f / 28672.0f, out, smem);
    else if (blockIdx.y == 1) dp_impl<2, 1024, 1024, 2048, 8>(Sxx, -0.5f / 28672.0f, out, smem);
    else                      dp_impl<2,  768,  768, 1536, 6>(Syy, -0.5f / 28672.0f, out, smem);
}

// ---------------- host launcher ----------------
extern "C" void kernel_launch(void* const* d_in, const int* in_sizes, int n_in,
                              void* d_out, int out_size, void* d_ws, size_t ws_size,
                              hipStream_t stream) {
    (void)in_sizes; (void)n_in; (void)out_size; (void)ws_size;
    const float* feats = (const float*)d_in[0];   // [16,1024,768]
    const float* targ  = (const float*)d_in[1];   // [16,768,768]
    const float* W     = (const float*)d_in[2];   // [768,128]
    const float* bias  = (const float*)d_in[3];   // [128]

    char* ws = (char*)d_ws;
    unsigned short* xbf = (unsigned short*)(ws + 0);            // 16384x128 bf16 = 4 MB
    unsigned short* ybf = (unsigned short*)(ws + 4194304);      // 12288x128 bf16 = 3 MB
    unsigned short* Wt  = (unsigned short*)(ws + 7340032);      // 128x768 bf16
    unsigned short* SxyE = (unsigned short*)(ws + 7536640);     // 16x1024x1792 bf16 E
    unsigned short* SxxE = (unsigned short*)(ws + 66256896);    // 16x1024x2048 bf16 E
    unsigned short* SyyE = (unsigned short*)(ws + 133365760);   // 16x768x1536  bf16 E

    hipMemsetAsync(d_out, 0, sizeof(float), stream);
    // zero all E streams so pad cells (invalid j) are E=0 -> alpha=0 automatically
    hipMemsetAsync(ws + 7536640, 0, 163577856, stream);

    wtrans_kernel<<<384, 256, 0, stream>>>(W, Wt);
    proj_kernel<<<128, 256, 0, stream>>>(feats, Wt, bias, xbf);
    proj_kernel<<<96, 256, 0, stream>>>(targ, Wt, bias, ybf);

    gram_kernel<<<dim3(8, 6, 16), 256, 0, stream>>>(xbf, ybf, SxyE, 1024,  768, 1792);
    gram_kernel<<<dim3(8, 8, 16), 256, 0, stream>>>(xbf, xbf, SxxE, 1024, 1024, 2048);
    gram_kernel<<<dim3(6, 6, 16), 256, 0, stream>>>(ybf, ybf, SyyE,  768,  768, 1536);

    // 8-wave cooperative DP (Syy: 6 active + 2 idle waves), 32-step chunks
    dp_kernel<<<dim3(16, 3), 512, 0, stream>>>(SxyE, SxxE, SyyE, (float*)d_out);
}